// Round 4
// baseline (229.418 us; speedup 1.0000x reference)
//
#include <hip/hip_runtime.h>

// ---------- types ----------
typedef __attribute__((ext_vector_type(8))) short bf16x8;   // 8 bf16 in 4 VGPRs
typedef __attribute__((ext_vector_type(4))) float f32x4;    // MFMA accumulator 16x16
typedef __attribute__((ext_vector_type(16))) float f32x16;  // MFMA accumulator 32x32

__device__ inline f32x4 mfma16(bf16x8 a, bf16x8 b, f32x4 c) {
    return __builtin_amdgcn_mfma_f32_16x16x32_bf16(a, b, c, 0, 0, 0);
}
__device__ inline f32x16 mfma32(bf16x8 a, bf16x8 b, f32x16 c) {
    return __builtin_amdgcn_mfma_f32_32x32x16_bf16(a, b, c, 0, 0, 0);
}

__device__ inline short f2bf(float f) {
    unsigned u = __builtin_bit_cast(unsigned, f);
    unsigned r = (u + 0x7fffu + ((u >> 16) & 1u)) >> 16;   // RNE
    return (short)r;
}
__device__ inline float bf2f(short h) {
    unsigned u = ((unsigned)(unsigned short)h) << 16;
    return __builtin_bit_cast(float, u);
}

__device__ inline unsigned cvt_pk_bf16(float lo, float hi) {
    unsigned r;
    asm("v_cvt_pk_bf16_f32 %0, %1, %2" : "=v"(r) : "v"(lo), "v"(hi));
    return r;
}
__device__ inline void plane_swap(unsigned& a, unsigned& b) {
    asm("v_permlane32_swap_b32 %0, %1" : "+v"(a), "+v"(b));
}

#define GAS(p) (const __attribute__((address_space(1))) void*)(p)
#define LAS(p) (__attribute__((address_space(3))) void*)(p)

// ---------- constants ----------
#define T_SEQ 4096
#define C_DIM 1024
#define N_HEAD 16
#define HEAD_DIM 64

// ---------- kernel 1: cast fp32 -> bf16 for x + 4 weights ----------
__global__ __launch_bounds__(256) void cast5(
    const float* __restrict__ s0, const float* __restrict__ s1,
    const float* __restrict__ s2, const float* __restrict__ s3,
    const float* __restrict__ s4,
    short* __restrict__ d0, short* __restrict__ d1, short* __restrict__ d2,
    short* __restrict__ d3, short* __restrict__ d4,
    int n0, int n1, int n2, int n3, int n4)
{
    int z = blockIdx.y;
    const float* s; short* d; int n;
    switch (z) {
        case 0: s = s0; d = d0; n = n0; break;
        case 1: s = s1; d = d1; n = n1; break;
        case 2: s = s2; d = d2; n = n2; break;
        case 3: s = s3; d = d3; n = n3; break;
        default: s = s4; d = d4; n = n4; break;
    }
    int i = (blockIdx.x * 256 + threadIdx.x) * 4;
    if (i >= n) return;
    float4 v = *(const float4*)&s[i];
    short4 o;
    o.x = f2bf(v.x); o.y = f2bf(v.y); o.z = f2bf(v.z); o.w = f2bf(v.w);
    *(short4*)&d[i] = o;
}

// ---------- kernel 2: NT GEMM via global_load_lds (m97 structure) ----------
template<int OBF>
__global__ __launch_bounds__(256) void gemm3(
    const short* __restrict__ A,
    const short* __restrict__ B0, const short* __restrict__ B1,
    const short* __restrict__ B2,
    void* C0, void* C1, void* C2,
    int M, int N, int K)
{
    const short* B = (blockIdx.z == 0) ? B0 : ((blockIdx.z == 1) ? B1 : B2);
    void*        C = (blockIdx.z == 0) ? C0 : ((blockIdx.z == 1) ? C1 : C2);

    __shared__ alignas(16) short sA[128 * 32];
    __shared__ alignas(16) short sB[128 * 32];

    int tid  = threadIdx.x;
    int wave = tid >> 6, lane = tid & 63;
    int lhi  = lane >> 4, llo = lane & 15;
    int wr   = wave >> 1, wc = wave & 1;
    int row0 = blockIdx.x * 128, col0 = blockIdx.y * 128;

    int srow = lane >> 2;
    int scol = (lane & 3) * 8;

    f32x4 acc[4][4];
#pragma unroll
    for (int m = 0; m < 4; m++)
#pragma unroll
        for (int n = 0; n < 4; n++)
            acc[m][n] = (f32x4){0.f, 0.f, 0.f, 0.f};

    for (int k0 = 0; k0 < K; k0 += 32) {
        __syncthreads();
#pragma unroll
        for (int s2 = 0; s2 < 2; s2++) {
            int rbase = wave * 32 + s2 * 16;
            __builtin_amdgcn_global_load_lds(
                GAS(&A[(size_t)(row0 + rbase + srow) * K + k0 + scol]),
                LAS(&sA[rbase * 32]), 16, 0, 0);
            __builtin_amdgcn_global_load_lds(
                GAS(&B[(size_t)(col0 + rbase + srow) * K + k0 + scol]),
                LAS(&sB[rbase * 32]), 16, 0, 0);
        }
        __syncthreads();

        bf16x8 af[4], bfv[4];
#pragma unroll
        for (int m = 0; m < 4; m++)
            af[m] = *(const bf16x8*)&sA[(wr * 64 + m * 16 + llo) * 32 + lhi * 8];
#pragma unroll
        for (int n = 0; n < 4; n++)
            bfv[n] = *(const bf16x8*)&sB[(wc * 64 + n * 16 + llo) * 32 + lhi * 8];
#pragma unroll
        for (int m = 0; m < 4; m++)
#pragma unroll
            for (int n = 0; n < 4; n++)
                acc[m][n] = mfma16(af[m], bfv[n], acc[m][n]);
    }

#pragma unroll
    for (int m = 0; m < 4; m++)
#pragma unroll
        for (int n = 0; n < 4; n++)
#pragma unroll
            for (int r = 0; r < 4; r++) {
                int row = row0 + wr * 64 + m * 16 + lhi * 4 + r;
                int col = col0 + wc * 64 + n * 16 + llo;
                float v = acc[m][n][r];
                if (OBF) ((short*)C)[(size_t)row * N + col] = f2bf(v);
                else     ((float*)C)[(size_t)row * N + col] = v;
            }
}

// ---------- kernel 3: RoPE + RMSNorm ----------
__global__ __launch_bounds__(256) void rope_rms(
    const short* __restrict__ Qb, const float* __restrict__ cosT,
    const float* __restrict__ sinT, short* __restrict__ qn, float outscale)
{
    int idx = blockIdx.x * 4 + (threadIdx.x >> 6);   // (t*16 + h)
    int t = idx >> 4, h = idx & 15;
    int d = threadIdx.x & 63;

    float v = bf2f(Qb[t * C_DIM + h * HEAD_DIM + d]);
    int d2 = d & 31;
    float c = cosT[t * 32 + d2], s = sinT[t * 32 + d2];
    float other = __shfl_xor(v, 32);
    float r = (d < 32) ? (v * c + other * s) : (v * c - other * s);

    float sq = r * r;
#pragma unroll
    for (int off = 32; off >= 1; off >>= 1) sq += __shfl_xor(sq, off);
    float inv = rsqrtf(sq * (1.0f / 64.0f) + 1e-6f);

    qn[((size_t)h * T_SEQ + t) * HEAD_DIM + d] = f2bf(r * inv * outscale);
}

// ---------- kernel 4: V transpose [T][C] -> [H][D][T] bf16, scaled ----------
__global__ __launch_bounds__(256) void vtrans(
    const short* __restrict__ Vb, short* __restrict__ vt)
{
    __shared__ short sT[64 * 65];
    int h = blockIdx.y, tb = blockIdx.x;
    int tid = threadIdx.x;
    const float inv64 = 1.0f / (64.0f + 1e-6f);
#pragma unroll
    for (int i = 0; i < 16; i++) {
        int linear = i * 256 + tid;
        int r = linear >> 6, c = linear & 63;
        float v = bf2f(Vb[(size_t)(tb * 64 + r) * C_DIM + h * HEAD_DIM + c]) * inv64;
        sT[c * 65 + r] = f2bf(v);
    }
    __syncthreads();
#pragma unroll
    for (int i = 0; i < 16; i++) {
        int linear = i * 256 + tid;
        int dd = linear >> 6, tt = linear & 63;
        vt[((size_t)(h * HEAD_DIM + dd)) * T_SEQ + tb * 64 + tt] = sT[dd * 65 + tt];
    }
}

// ---------- kernel 5: attention, register-pipelined K/V ----------
// qn,kn: [H][T][D] bf16 (q pre-scaled 1/8). vt: [H][D][T] bf16 (pre-scaled 1/64.000001).
// Grid: 1024 blocks = 8 xcd x 2 heads x 64 q-tiles (64 rows). Block: 4 waves =
// 2 q-bands x 2 kv-teams. Per 32-kv chunk: 8 b128 K/V loads double-buffered in
// registers, prefetched one chunk ahead, pinned with sched_barrier(0).
// P never touches LDS (cvt_pk + permlane32_swap). LDS only for team reduce.

#define LOADCHUNK(k0_, k1_, k2_, k3_, v0_, v1_, v2_, v3_, c_) do {              \
    int base_ = ((c_) >> 1) * 128 + team * 64 + ((c_) & 1) * 32;                \
    const short* Kr_ = &Kh[(size_t)(base_ + lo) * HEAD_DIM + hi * 8];           \
    k0_ = *(const bf16x8*)&Kr_[0];  k1_ = *(const bf16x8*)&Kr_[16];             \
    k2_ = *(const bf16x8*)&Kr_[32]; k3_ = *(const bf16x8*)&Kr_[48];             \
    const short* Vr_ = &Vh[(size_t)lo * T_SEQ + base_ + hi * 8];                \
    v0_ = *(const bf16x8*)&Vr_[0];                                              \
    v1_ = *(const bf16x8*)&Vr_[16];                                             \
    v2_ = *(const bf16x8*)&Vr_[(size_t)32 * T_SEQ];                             \
    v3_ = *(const bf16x8*)&Vr_[(size_t)32 * T_SEQ + 16];                        \
} while (0)

#define COMPUTECHUNK(k0_, k1_, k2_, k3_, v0_, v1_, v2_, v3_, c_) do {           \
    int base_ = ((c_) >> 1) * 128 + team * 64 + ((c_) & 1) * 32;                \
    int diag_ = ((c_) >> 1) == nk - 1;                                          \
    f32x16 sv;                                                                  \
    _Pragma("unroll") for (int r = 0; r < 16; r++) sv[r] = 0.f;                 \
    __builtin_amdgcn_s_setprio(1);                                              \
    sv = mfma32(k0_, qf0, sv);                                                  \
    sv = mfma32(k1_, qf1, sv);                                                  \
    sv = mfma32(k2_, qf2, sv);                                                  \
    sv = mfma32(k3_, qf3, sv);                                                  \
    __builtin_amdgcn_s_setprio(0);                                              \
    if (diag_) {                                                                \
        _Pragma("unroll") for (int r = 0; r < 16; r++) {                        \
            int kvg_ = base_ + (r & 3) + 8 * (r >> 2) + 4 * hi;                 \
            float pv_ = __builtin_amdgcn_rcpf(1.f + __expf(-sv[r]));            \
            sv[r] = (kvg_ <= qrow) ? pv_ : 0.f;                                 \
        }                                                                       \
    } else {                                                                    \
        _Pragma("unroll") for (int r = 0; r < 16; r++)                          \
            sv[r] = __builtin_amdgcn_rcpf(1.f + __expf(-sv[r]));                \
    }                                                                           \
    _Pragma("unroll") for (int k2i = 0; k2i < 2; k2i++) {                       \
        unsigned wA = cvt_pk_bf16(sv[8 * k2i + 0], sv[8 * k2i + 1]);            \
        unsigned wC = cvt_pk_bf16(sv[8 * k2i + 2], sv[8 * k2i + 3]);            \
        unsigned wB = cvt_pk_bf16(sv[8 * k2i + 4], sv[8 * k2i + 5]);            \
        unsigned wD = cvt_pk_bf16(sv[8 * k2i + 6], sv[8 * k2i + 7]);            \
        plane_swap(wA, wB);                                                     \
        plane_swap(wC, wD);                                                     \
        union { unsigned u[4]; bf16x8 v; } pw_;                                 \
        pw_.u[0] = wA; pw_.u[1] = wC; pw_.u[2] = wB; pw_.u[3] = wD;             \
        __builtin_amdgcn_s_setprio(1);                                          \
        yac0 = mfma32(pw_.v, k2i ? v1_ : v0_, yac0);                            \
        yac1 = mfma32(pw_.v, k2i ? v3_ : v2_, yac1);                            \
        __builtin_amdgcn_s_setprio(0);                                          \
    }                                                                           \
} while (0)

__global__ __launch_bounds__(256, 3) void attn4(
    const short* __restrict__ qn, const short* __restrict__ kn,
    const short* __restrict__ vt, short* __restrict__ yb)
{
    __shared__ alignas(16) float Yred[2 * 32 * 64];   // 16 KiB

    int id  = blockIdx.x;
    int h   = (id & 7) * 2 + ((id >> 3) & 1);         // 2 heads per XCD slot
    int ord = id >> 4;                                 // 0..63
    int rr  = ord >> 4, j = ord & 15;
    int t   = (rr == 0) ? (63 - j) : (rr == 1) ? (47 - j) : (rr == 2) ? (16 + j) : j;
    int nk  = (t >> 1) + 1;                            // 128-wide k-tiles

    int tid = threadIdx.x, wave = tid >> 6, lane = tid & 63;
    int lo = lane & 31, hi = lane >> 5;
    int band = wave & 1, team = wave >> 1;

    const short* Qh = qn + (size_t)h * T_SEQ * HEAD_DIM;
    const short* Kh = kn + (size_t)h * T_SEQ * HEAD_DIM;
    const short* Vh = vt + (size_t)h * HEAD_DIM * T_SEQ;

    int q0 = t * 64;
    int qrow = q0 + band * 32 + lo;

    const short* Qr = &Qh[(size_t)qrow * HEAD_DIM + hi * 8];
    bf16x8 qf0 = *(const bf16x8*)&Qr[0];
    bf16x8 qf1 = *(const bf16x8*)&Qr[16];
    bf16x8 qf2 = *(const bf16x8*)&Qr[32];
    bf16x8 qf3 = *(const bf16x8*)&Qr[48];

    f32x16 yac0, yac1;
#pragma unroll
    for (int r = 0; r < 16; r++) { yac0[r] = 0.f; yac1[r] = 0.f; }

    bf16x8 kA0, kA1, kA2, kA3, vA0, vA1, vA2, vA3;     // buffer A
    bf16x8 kB0, kB1, kB2, kB3, vB0, vB1, vB2, vB3;     // buffer B

    int nc = nk * 2;                                   // 32-kv chunks (even)
    LOADCHUNK(kA0, kA1, kA2, kA3, vA0, vA1, vA2, vA3, 0);
    for (int c = 0; c < nc; c += 2) {
        LOADCHUNK(kB0, kB1, kB2, kB3, vB0, vB1, vB2, vB3, c + 1);
        __builtin_amdgcn_sched_barrier(0);
        COMPUTECHUNK(kA0, kA1, kA2, kA3, vA0, vA1, vA2, vA3, c);
        if (c + 2 < nc) {
            LOADCHUNK(kA0, kA1, kA2, kA3, vA0, vA1, vA2, vA3, c + 2);
        }
        __builtin_amdgcn_sched_barrier(0);
        COMPUTECHUNK(kB0, kB1, kB2, kB3, vB0, vB1, vB2, vB3, c + 1);
    }

    // ---- cross-team reduce (kv halves) + store ----
    if (team == 1) {
#pragma unroll
        for (int d = 0; d < 2; d++)
#pragma unroll
            for (int r = 0; r < 16; r++) {
                int crow = (r & 3) + 8 * (r >> 2) + 4 * hi;
                Yred[(band * 32 + crow) * 64 + d * 32 + lo] = d ? yac1[r] : yac0[r];
            }
    }
    __syncthreads();
    if (team == 0) {
#pragma unroll
        for (int d = 0; d < 2; d++)
#pragma unroll
            for (int r = 0; r < 16; r++) {
                int crow = (r & 3) + 8 * (r >> 2) + 4 * hi;
                float v = (d ? yac1[r] : yac0[r]) + Yred[(band * 32 + crow) * 64 + d * 32 + lo];
                yb[(size_t)(q0 + band * 32 + crow) * C_DIM + h * HEAD_DIM + d * 32 + lo] = f2bf(v);
            }
    }
}

// ---------- launch ----------
extern "C" void kernel_launch(void* const* d_in, const int* in_sizes, int n_in,
                              void* d_out, int out_size, void* d_ws, size_t ws_size,
                              hipStream_t stream)
{
    const float* x    = (const float*)d_in[0];
    const float* cosT = (const float*)d_in[1];
    const float* sinT = (const float*)d_in[2];
    const float* wq   = (const float*)d_in[3];
    const float* wk   = (const float*)d_in[4];
    const float* wv   = (const float*)d_in[5];
    const float* wp   = (const float*)d_in[6];

    char* ws = (char*)d_ws;
    const size_t MB = 1024 * 1024;
    short* xb  = (short*)(ws + 0);
    short* wqb = (short*)(ws + 8  * MB);
    short* wkb = (short*)(ws + 10 * MB);
    short* wvb = (short*)(ws + 12 * MB);
    short* wpb = (short*)(ws + 14 * MB);
    short* Qb  = (short*)(ws + 16 * MB);
    short* Kb  = (short*)(ws + 24 * MB);
    short* Vb  = (short*)(ws + 32 * MB);
    short* qnb = (short*)(ws + 40 * MB);
    short* knb = (short*)(ws + 48 * MB);
    short* vtb = (short*)(ws + 56 * MB);
    short* yb  = (short*)(ws + 64 * MB);

    cast5<<<dim3(4096, 5, 1), 256, 0, stream>>>(
        x, wq, wk, wv, wp, xb, wqb, wkb, wvb, wpb,
        T_SEQ * C_DIM, C_DIM * C_DIM, C_DIM * C_DIM, C_DIM * C_DIM, C_DIM * C_DIM);

    gemm3<1><<<dim3(32, 8, 3), 256, 0, stream>>>(
        xb, wqb, wkb, wvb, (void*)Qb, (void*)Kb, (void*)Vb, T_SEQ, C_DIM, C_DIM);

    rope_rms<<<16384, 256, 0, stream>>>(Qb, cosT, sinT, qnb, 0.125f);
    rope_rms<<<16384, 256, 0, stream>>>(Kb, cosT, sinT, knb, 1.0f);

    vtrans<<<dim3(64, 16, 1), 256, 0, stream>>>(Vb, vtb);

    attn4<<<1024, 256, 0, stream>>>(qnb, knb, vtb, yb);

    gemm3<0><<<dim3(32, 8, 1), 256, 0, stream>>>(
        yb, wpb, wpb, wpb, d_out, d_out, d_out, T_SEQ, C_DIM, C_DIM);
}

// Round 5
// 159.354 us; speedup vs baseline: 1.4397x; 1.4397x over previous
//
#include <hip/hip_runtime.h>

// ---------- types ----------
typedef __attribute__((ext_vector_type(8))) short bf16x8;   // 8 bf16 in 4 VGPRs
typedef __attribute__((ext_vector_type(4))) float f32x4;    // MFMA accumulator 16x16
typedef __attribute__((ext_vector_type(16))) float f32x16;  // MFMA accumulator 32x32

__device__ inline f32x4 mfma16(bf16x8 a, bf16x8 b, f32x4 c) {
    return __builtin_amdgcn_mfma_f32_16x16x32_bf16(a, b, c, 0, 0, 0);
}
__device__ inline f32x16 mfma32(bf16x8 a, bf16x8 b, f32x16 c) {
    return __builtin_amdgcn_mfma_f32_32x32x16_bf16(a, b, c, 0, 0, 0);
}

__device__ inline short f2bf(float f) {
    unsigned u = __builtin_bit_cast(unsigned, f);
    unsigned r = (u + 0x7fffu + ((u >> 16) & 1u)) >> 16;   // RNE
    return (short)r;
}
__device__ inline float bf2f(short h) {
    unsigned u = ((unsigned)(unsigned short)h) << 16;
    return __builtin_bit_cast(float, u);
}

__device__ inline unsigned cvt_pk_bf16(float lo, float hi) {
    unsigned r;
    asm("v_cvt_pk_bf16_f32 %0, %1, %2" : "=v"(r) : "v"(lo), "v"(hi));
    return r;
}
__device__ inline void plane_swap(unsigned& a, unsigned& b) {
    asm("v_permlane32_swap_b32 %0, %1" : "+v"(a), "+v"(b));
}
__device__ inline float exp2_hw(float x) {
    float r;
    asm("v_exp_f32 %0, %1" : "=v"(r) : "v"(x));
    return r;
}

#define GAS(p) (const __attribute__((address_space(1))) void*)(p)
#define LAS(p) (__attribute__((address_space(3))) void*)(p)

// ---------- constants ----------
#define T_SEQ 4096
#define C_DIM 1024
#define N_HEAD 16
#define HEAD_DIM 64
// -log2(e)/8 folded into q so sigmoid(x) = rcp(1 + exp2(sv))
#define QSCALE (-0.18033688011112042f)

// ---------- kernel 1: cast fp32 -> bf16 for x + 4 weights ----------
__global__ __launch_bounds__(256) void cast5(
    const float* __restrict__ s0, const float* __restrict__ s1,
    const float* __restrict__ s2, const float* __restrict__ s3,
    const float* __restrict__ s4,
    short* __restrict__ d0, short* __restrict__ d1, short* __restrict__ d2,
    short* __restrict__ d3, short* __restrict__ d4,
    int n0, int n1, int n2, int n3, int n4)
{
    int z = blockIdx.y;
    const float* s; short* d; int n;
    switch (z) {
        case 0: s = s0; d = d0; n = n0; break;
        case 1: s = s1; d = d1; n = n1; break;
        case 2: s = s2; d = d2; n = n2; break;
        case 3: s = s3; d = d3; n = n3; break;
        default: s = s4; d = d4; n = n4; break;
    }
    int i = (blockIdx.x * 256 + threadIdx.x) * 4;
    if (i >= n) return;
    float4 v = *(const float4*)&s[i];
    short4 o;
    o.x = f2bf(v.x); o.y = f2bf(v.y); o.z = f2bf(v.z); o.w = f2bf(v.w);
    *(short4*)&d[i] = o;
}

// ---------- kernel 2: NT GEMM via global_load_lds (m97 structure) ----------
template<int OBF>
__global__ __launch_bounds__(256) void gemm3(
    const short* __restrict__ A,
    const short* __restrict__ B0, const short* __restrict__ B1,
    const short* __restrict__ B2,
    void* C0, void* C1, void* C2,
    int M, int N, int K)
{
    const short* B = (blockIdx.z == 0) ? B0 : ((blockIdx.z == 1) ? B1 : B2);
    void*        C = (blockIdx.z == 0) ? C0 : ((blockIdx.z == 1) ? C1 : C2);

    __shared__ alignas(16) short sA[128 * 32];
    __shared__ alignas(16) short sB[128 * 32];

    int tid  = threadIdx.x;
    int wave = tid >> 6, lane = tid & 63;
    int lhi  = lane >> 4, llo = lane & 15;
    int wr   = wave >> 1, wc = wave & 1;
    int row0 = blockIdx.x * 128, col0 = blockIdx.y * 128;

    int srow = lane >> 2;
    int scol = (lane & 3) * 8;

    f32x4 acc[4][4];
#pragma unroll
    for (int m = 0; m < 4; m++)
#pragma unroll
        for (int n = 0; n < 4; n++)
            acc[m][n] = (f32x4){0.f, 0.f, 0.f, 0.f};

    for (int k0 = 0; k0 < K; k0 += 32) {
        __syncthreads();
#pragma unroll
        for (int s2 = 0; s2 < 2; s2++) {
            int rbase = wave * 32 + s2 * 16;
            __builtin_amdgcn_global_load_lds(
                GAS(&A[(size_t)(row0 + rbase + srow) * K + k0 + scol]),
                LAS(&sA[rbase * 32]), 16, 0, 0);
            __builtin_amdgcn_global_load_lds(
                GAS(&B[(size_t)(col0 + rbase + srow) * K + k0 + scol]),
                LAS(&sB[rbase * 32]), 16, 0, 0);
        }
        __syncthreads();

        bf16x8 af[4], bfv[4];
#pragma unroll
        for (int m = 0; m < 4; m++)
            af[m] = *(const bf16x8*)&sA[(wr * 64 + m * 16 + llo) * 32 + lhi * 8];
#pragma unroll
        for (int n = 0; n < 4; n++)
            bfv[n] = *(const bf16x8*)&sB[(wc * 64 + n * 16 + llo) * 32 + lhi * 8];
#pragma unroll
        for (int m = 0; m < 4; m++)
#pragma unroll
            for (int n = 0; n < 4; n++)
                acc[m][n] = mfma16(af[m], bfv[n], acc[m][n]);
    }

#pragma unroll
    for (int m = 0; m < 4; m++)
#pragma unroll
        for (int n = 0; n < 4; n++)
#pragma unroll
            for (int r = 0; r < 4; r++) {
                int row = row0 + wr * 64 + m * 16 + lhi * 4 + r;
                int col = col0 + wc * 64 + n * 16 + llo;
                float v = acc[m][n][r];
                if (OBF) ((short*)C)[(size_t)row * N + col] = f2bf(v);
                else     ((float*)C)[(size_t)row * N + col] = v;
            }
}

// ---------- kernel 3: RoPE + RMSNorm ----------
__global__ __launch_bounds__(256) void rope_rms(
    const short* __restrict__ Qb, const float* __restrict__ cosT,
    const float* __restrict__ sinT, short* __restrict__ qn, float outscale)
{
    int idx = blockIdx.x * 4 + (threadIdx.x >> 6);   // (t*16 + h)
    int t = idx >> 4, h = idx & 15;
    int d = threadIdx.x & 63;

    float v = bf2f(Qb[t * C_DIM + h * HEAD_DIM + d]);
    int d2 = d & 31;
    float c = cosT[t * 32 + d2], s = sinT[t * 32 + d2];
    float other = __shfl_xor(v, 32);
    float r = (d < 32) ? (v * c + other * s) : (v * c - other * s);

    float sq = r * r;
#pragma unroll
    for (int off = 32; off >= 1; off >>= 1) sq += __shfl_xor(sq, off);
    float inv = rsqrtf(sq * (1.0f / 64.0f) + 1e-6f);

    qn[((size_t)h * T_SEQ + t) * HEAD_DIM + d] = f2bf(r * inv * outscale);
}

// ---------- kernel 4: V transpose [T][C] -> [H][D][T] bf16, scaled ----------
__global__ __launch_bounds__(256) void vtrans(
    const short* __restrict__ Vb, short* __restrict__ vt)
{
    __shared__ short sT[64 * 65];
    int h = blockIdx.y, tb = blockIdx.x;
    int tid = threadIdx.x;
    const float inv64 = 1.0f / (64.0f + 1e-6f);
#pragma unroll
    for (int i = 0; i < 16; i++) {
        int linear = i * 256 + tid;
        int r = linear >> 6, c = linear & 63;
        float v = bf2f(Vb[(size_t)(tb * 64 + r) * C_DIM + h * HEAD_DIM + c]) * inv64;
        sT[c * 65 + r] = f2bf(v);
    }
    __syncthreads();
#pragma unroll
    for (int i = 0; i < 16; i++) {
        int linear = i * 256 + tid;
        int dd = linear >> 6, tt = linear & 63;
        vt[((size_t)(h * HEAD_DIM + dd)) * T_SEQ + tb * 64 + tt] = sT[dd * 65 + tt];
    }
}

// ---------- kernel 5: attention, LDS-staged K/V with async pipeline ----------
// qn: [H][T][D] bf16 pre-scaled by -log2e/8; kn: [H][T][D]; vt: [H][D][T] pre-scaled.
// Grid 512 = 16 heads x 32 q-tiles(128), paired (t, 31-t) for balance.
// Block: 8 waves = 4 q-bands(32) x 2 kv-teams(32 of each 64-kv step).
// Per step: K[64][64] + V^T[64][64] staged to LDS dbuf via global_load_lds with
// pre-swizzled source (read side XORs (row&7)<<4); counted vmcnt(2) keeps next
// stage in flight across raw s_barriers. P path stays in registers
// (cvt_pk_bf16 + permlane32_swap). Epilogue: cross-team LDS reduce.

#define STAGE(s_, bf_) do {                                                      \
    int kb_ = (s_) * 64;                                                         \
    int r0_ = wv * 8 + (lane >> 3);                                              \
    int ss_ = (lane & 7) ^ (lane >> 3);                                          \
    __builtin_amdgcn_global_load_lds(                                            \
        GAS(Kh + (size_t)(kb_ + r0_) * HEAD_DIM + ss_ * 8),                      \
        LAS(Smem + (bf_) * 8192 + wv * 1024), 16, 0, 0);                         \
    __builtin_amdgcn_global_load_lds(                                            \
        GAS(Vh + (size_t)r0_ * T_SEQ + kb_ + ss_ * 8),                           \
        LAS(Smem + 16384 + (bf_) * 8192 + wv * 1024), 16, 0, 0);                 \
} while (0)

__global__ __launch_bounds__(512, 4) void attn5(
    const short* __restrict__ qn, const short* __restrict__ kn,
    const short* __restrict__ vt, short* __restrict__ yb)
{
    __shared__ alignas(16) char Smem[32768];   // K dbuf 16K | V dbuf 16K; Yred overlay

    int id  = blockIdx.x;
    int idx = id >> 3;
    int h   = (id & 7) * 2 + (idx & 1);
    int sq  = idx >> 1;                              // 0..31
    int t   = (sq < 16) ? (31 - sq) : (sq - 16);     // heavy-first, pair sums uniform
    int ns  = 2 * t + 2;                             // 64-kv steps

    int tid = threadIdx.x, wv = tid >> 6, lane = tid & 63;
    int lo = lane & 31, hi = lane >> 5;
    int band = wv & 3, tm = wv >> 2;

    const short* Qh = qn + (size_t)h * T_SEQ * HEAD_DIM;
    const short* Kh = kn + (size_t)h * T_SEQ * HEAD_DIM;
    const short* Vh = vt + (size_t)h * HEAD_DIM * T_SEQ;

    int q0 = t * 128;
    int qrow  = q0 + band * 32 + lo;                 // this lane's q index
    int qmaxw = q0 + band * 32 + 31;                 // wave's max q

    const short* Qr = &Qh[(size_t)qrow * HEAD_DIM + hi * 8];
    bf16x8 qf0 = *(const bf16x8*)&Qr[0];
    bf16x8 qf1 = *(const bf16x8*)&Qr[16];
    bf16x8 qf2 = *(const bf16x8*)&Qr[32];
    bf16x8 qf3 = *(const bf16x8*)&Qr[48];

    f32x16 yac0, yac1;
#pragma unroll
    for (int r = 0; r < 16; r++) { yac0[r] = 0.f; yac1[r] = 0.f; }

    unsigned swz   = (unsigned)((lo & 7) << 4);
    unsigned krow  = (unsigned)((tm * 32 + lo) * 128);
    unsigned vbase = 16384u;

    STAGE(0, 0);
    int buf = 0;
    for (int s = 0; s < ns; s++) {
        if (s + 1 < ns) {
            STAGE(s + 1, buf ^ 1);
            asm volatile("s_waitcnt vmcnt(2)" ::: "memory");
        } else {
            asm volatile("s_waitcnt vmcnt(0)" ::: "memory");
        }
        __builtin_amdgcn_s_barrier();

        int kb0 = s * 64 + tm * 32;                  // my chunk's global kv base
        if (kb0 <= qmaxw) {
            const char* KB = Smem + buf * 8192;
            const char* VB = Smem + vbase + buf * 8192;
            // K fragments (A-operand), swizzled
            bf16x8 kf0 = *(const bf16x8*)(KB + krow + ((0u * 32 + hi * 16) ^ swz));
            bf16x8 kf1 = *(const bf16x8*)(KB + krow + ((1u * 32 + hi * 16) ^ swz));
            bf16x8 kf2 = *(const bf16x8*)(KB + krow + ((2u * 32 + hi * 16) ^ swz));
            bf16x8 kf3 = *(const bf16x8*)(KB + krow + ((3u * 32 + hi * 16) ^ swz));
            // V fragments (B-operand) issued early, consumed after sigmoid
            unsigned v0r = (unsigned)((0 * 32 + lo) * 128);
            unsigned v1r = (unsigned)((1 * 32 + lo) * 128);
            unsigned vswz = (unsigned)((lo & 7) << 4);
            bf16x8 vf00 = *(const bf16x8*)(VB + v0r + (((unsigned)(tm * 64 + 0 * 32 + hi * 16)) ^ vswz));
            bf16x8 vf01 = *(const bf16x8*)(VB + v0r + (((unsigned)(tm * 64 + 1 * 32 + hi * 16)) ^ vswz));
            bf16x8 vf10 = *(const bf16x8*)(VB + v1r + (((unsigned)(tm * 64 + 0 * 32 + hi * 16)) ^ vswz));
            bf16x8 vf11 = *(const bf16x8*)(VB + v1r + (((unsigned)(tm * 64 + 1 * 32 + hi * 16)) ^ vswz));

            f32x16 sv;
#pragma unroll
            for (int r = 0; r < 16; r++) sv[r] = 0.f;
            __builtin_amdgcn_s_setprio(1);
            sv = mfma32(kf0, qf0, sv);
            sv = mfma32(kf1, qf1, sv);
            sv = mfma32(kf2, qf2, sv);
            sv = mfma32(kf3, qf3, sv);
            __builtin_amdgcn_s_setprio(0);

            // sigmoid: p = rcp(1 + exp2(sv))  (q pre-scaled by -log2e/8)
            if (kb0 + 31 > q0 + band * 32) {         // diagonal chunk: element mask
#pragma unroll
                for (int r = 0; r < 16; r++) {
                    int kvg = kb0 + (r & 3) + 8 * (r >> 2) + 4 * hi;
                    float pv = __builtin_amdgcn_rcpf(1.f + exp2_hw(sv[r]));
                    sv[r] = (kvg <= qrow) ? pv : 0.f;
                }
            } else {
#pragma unroll
                for (int r = 0; r < 16; r++)
                    sv[r] = __builtin_amdgcn_rcpf(1.f + exp2_hw(sv[r]));
            }

            // P re-layout in-register + PV
#pragma unroll
            for (int k2 = 0; k2 < 2; k2++) {
                unsigned wA = cvt_pk_bf16(sv[8 * k2 + 0], sv[8 * k2 + 1]);
                unsigned wC = cvt_pk_bf16(sv[8 * k2 + 2], sv[8 * k2 + 3]);
                unsigned wB = cvt_pk_bf16(sv[8 * k2 + 4], sv[8 * k2 + 5]);
                unsigned wD = cvt_pk_bf16(sv[8 * k2 + 6], sv[8 * k2 + 7]);
                plane_swap(wA, wB);
                plane_swap(wC, wD);
                union { unsigned u[4]; bf16x8 v; } pw;
                pw.u[0] = wA; pw.u[1] = wC; pw.u[2] = wB; pw.u[3] = wD;
                __builtin_amdgcn_s_setprio(1);
                yac0 = mfma32(pw.v, k2 ? vf01 : vf00, yac0);
                yac1 = mfma32(pw.v, k2 ? vf11 : vf10, yac1);
                __builtin_amdgcn_s_setprio(0);
            }
        }
        asm volatile("" ::: "memory");
        __builtin_amdgcn_s_barrier();
        buf ^= 1;
    }

    // ---- cross-team reduce (kv halves) + store ----
    __syncthreads();
    float* Yred = (float*)Smem;                      // overlay on staging buffers
    if (tm == 1) {
#pragma unroll
        for (int d = 0; d < 2; d++)
#pragma unroll
            for (int r = 0; r < 16; r++) {
                int crow = (r & 3) + 8 * (r >> 2) + 4 * hi;
                Yred[(band * 32 + crow) * 64 + d * 32 + lo] = d ? yac1[r] : yac0[r];
            }
    }
    __syncthreads();
    if (tm == 0) {
#pragma unroll
        for (int d = 0; d < 2; d++)
#pragma unroll
            for (int r = 0; r < 16; r++) {
                int crow = (r & 3) + 8 * (r >> 2) + 4 * hi;
                float v = (d ? yac1[r] : yac0[r]) + Yred[(band * 32 + crow) * 64 + d * 32 + lo];
                yb[(size_t)(q0 + band * 32 + crow) * C_DIM + h * HEAD_DIM + d * 32 + lo] = f2bf(v);
            }
    }
}

// ---------- launch ----------
extern "C" void kernel_launch(void* const* d_in, const int* in_sizes, int n_in,
                              void* d_out, int out_size, void* d_ws, size_t ws_size,
                              hipStream_t stream)
{
    const float* x    = (const float*)d_in[0];
    const float* cosT = (const float*)d_in[1];
    const float* sinT = (const float*)d_in[2];
    const float* wq   = (const float*)d_in[3];
    const float* wk   = (const float*)d_in[4];
    const float* wv   = (const float*)d_in[5];
    const float* wp   = (const float*)d_in[6];

    char* ws = (char*)d_ws;
    const size_t MB = 1024 * 1024;
    short* xb  = (short*)(ws + 0);
    short* wqb = (short*)(ws + 8  * MB);
    short* wkb = (short*)(ws + 10 * MB);
    short* wvb = (short*)(ws + 12 * MB);
    short* wpb = (short*)(ws + 14 * MB);
    short* Qb  = (short*)(ws + 16 * MB);
    short* Kb  = (short*)(ws + 24 * MB);
    short* Vb  = (short*)(ws + 32 * MB);
    short* qnb = (short*)(ws + 40 * MB);
    short* knb = (short*)(ws + 48 * MB);
    short* vtb = (short*)(ws + 56 * MB);
    short* yb  = (short*)(ws + 64 * MB);

    cast5<<<dim3(4096, 5, 1), 256, 0, stream>>>(
        x, wq, wk, wv, wp, xb, wqb, wkb, wvb, wpb,
        T_SEQ * C_DIM, C_DIM * C_DIM, C_DIM * C_DIM, C_DIM * C_DIM, C_DIM * C_DIM);

    gemm3<1><<<dim3(32, 8, 3), 256, 0, stream>>>(
        xb, wqb, wkb, wvb, (void*)Qb, (void*)Kb, (void*)Vb, T_SEQ, C_DIM, C_DIM);

    rope_rms<<<16384, 256, 0, stream>>>(Qb, cosT, sinT, qnb, QSCALE);
    rope_rms<<<16384, 256, 0, stream>>>(Kb, cosT, sinT, knb, 1.0f);

    vtrans<<<dim3(64, 16, 1), 256, 0, stream>>>(Vb, vtb);

    attn5<<<512, 512, 0, stream>>>(qnb, knb, vtb, yb);

    gemm3<0><<<dim3(32, 8, 1), 256, 0, stream>>>(
        yb, wpb, wpb, wpb, d_out, d_out, d_out, T_SEQ, C_DIM, C_DIM);
}

// Round 6
// 142.295 us; speedup vs baseline: 1.6123x; 1.1199x over previous
//
#include <hip/hip_runtime.h>

// ---------- types ----------
typedef __attribute__((ext_vector_type(8))) short bf16x8;   // 8 bf16 in 4 VGPRs
typedef __attribute__((ext_vector_type(4))) float f32x4;    // MFMA accumulator 16x16
typedef __attribute__((ext_vector_type(16))) float f32x16;  // MFMA accumulator 32x32

__device__ inline f32x4 mfma16(bf16x8 a, bf16x8 b, f32x4 c) {
    return __builtin_amdgcn_mfma_f32_16x16x32_bf16(a, b, c, 0, 0, 0);
}
__device__ inline f32x16 mfma32(bf16x8 a, bf16x8 b, f32x16 c) {
    return __builtin_amdgcn_mfma_f32_32x32x16_bf16(a, b, c, 0, 0, 0);
}

__device__ inline short f2bf(float f) {
    unsigned u = __builtin_bit_cast(unsigned, f);
    unsigned r = (u + 0x7fffu + ((u >> 16) & 1u)) >> 16;   // RNE
    return (short)r;
}
__device__ inline float bf2f(short h) {
    unsigned u = ((unsigned)(unsigned short)h) << 16;
    return __builtin_bit_cast(float, u);
}

__device__ inline unsigned cvt_pk_bf16(float lo, float hi) {
    unsigned r;
    asm("v_cvt_pk_bf16_f32 %0, %1, %2" : "=v"(r) : "v"(lo), "v"(hi));
    return r;
}
__device__ inline void plane_swap(unsigned& a, unsigned& b) {
    asm("v_permlane32_swap_b32 %0, %1" : "+v"(a), "+v"(b));
}
__device__ inline float exp2_hw(float x) {
    float r;
    asm("v_exp_f32 %0, %1" : "=v"(r) : "v"(x));
    return r;
}

#define GAS(p) (const __attribute__((address_space(1))) void*)(p)
#define LAS(p) (__attribute__((address_space(3))) void*)(p)

// ---------- constants ----------
#define T_SEQ 4096
#define C_DIM 1024
#define N_HEAD 16
#define HEAD_DIM 64
// -log2(e)/8 folded into q so sigmoid(x) = rcp(1 + exp2(sv))
#define QSCALE (-0.18033688011112042f)

// ---------- kernel 1: cast fp32 -> bf16 for x + 4 weights ----------
__global__ __launch_bounds__(256) void cast5(
    const float* __restrict__ s0, const float* __restrict__ s1,
    const float* __restrict__ s2, const float* __restrict__ s3,
    const float* __restrict__ s4,
    short* __restrict__ d0, short* __restrict__ d1, short* __restrict__ d2,
    short* __restrict__ d3, short* __restrict__ d4,
    int n0, int n1, int n2, int n3, int n4)
{
    int z = blockIdx.y;
    const float* s; short* d; int n;
    switch (z) {
        case 0: s = s0; d = d0; n = n0; break;
        case 1: s = s1; d = d1; n = n1; break;
        case 2: s = s2; d = d2; n = n2; break;
        case 3: s = s3; d = d3; n = n3; break;
        default: s = s4; d = d4; n = n4; break;
    }
    int i = (blockIdx.x * 256 + threadIdx.x) * 4;
    if (i >= n) return;
    float4 v = *(const float4*)&s[i];
    short4 o;
    o.x = f2bf(v.x); o.y = f2bf(v.y); o.z = f2bf(v.z); o.w = f2bf(v.w);
    *(short4*)&d[i] = o;
}

// ---------- kernel 2: NT GEMM via global_load_lds (m97 structure) ----------
template<int OBF>
__global__ __launch_bounds__(256) void gemm3(
    const short* __restrict__ A,
    const short* __restrict__ B0, const short* __restrict__ B1,
    const short* __restrict__ B2,
    void* C0, void* C1, void* C2,
    int M, int N, int K)
{
    const short* B = (blockIdx.z == 0) ? B0 : ((blockIdx.z == 1) ? B1 : B2);
    void*        C = (blockIdx.z == 0) ? C0 : ((blockIdx.z == 1) ? C1 : C2);

    __shared__ alignas(16) short sA[128 * 32];
    __shared__ alignas(16) short sB[128 * 32];

    int tid  = threadIdx.x;
    int wave = tid >> 6, lane = tid & 63;
    int lhi  = lane >> 4, llo = lane & 15;
    int wr   = wave >> 1, wc = wave & 1;
    int row0 = blockIdx.x * 128, col0 = blockIdx.y * 128;

    int srow = lane >> 2;
    int scol = (lane & 3) * 8;

    f32x4 acc[4][4];
#pragma unroll
    for (int m = 0; m < 4; m++)
#pragma unroll
        for (int n = 0; n < 4; n++)
            acc[m][n] = (f32x4){0.f, 0.f, 0.f, 0.f};

    for (int k0 = 0; k0 < K; k0 += 32) {
        __syncthreads();
#pragma unroll
        for (int s2 = 0; s2 < 2; s2++) {
            int rbase = wave * 32 + s2 * 16;
            __builtin_amdgcn_global_load_lds(
                GAS(&A[(size_t)(row0 + rbase + srow) * K + k0 + scol]),
                LAS(&sA[rbase * 32]), 16, 0, 0);
            __builtin_amdgcn_global_load_lds(
                GAS(&B[(size_t)(col0 + rbase + srow) * K + k0 + scol]),
                LAS(&sB[rbase * 32]), 16, 0, 0);
        }
        __syncthreads();

        bf16x8 af[4], bfv[4];
#pragma unroll
        for (int m = 0; m < 4; m++)
            af[m] = *(const bf16x8*)&sA[(wr * 64 + m * 16 + llo) * 32 + lhi * 8];
#pragma unroll
        for (int n = 0; n < 4; n++)
            bfv[n] = *(const bf16x8*)&sB[(wc * 64 + n * 16 + llo) * 32 + lhi * 8];
#pragma unroll
        for (int m = 0; m < 4; m++)
#pragma unroll
            for (int n = 0; n < 4; n++)
                acc[m][n] = mfma16(af[m], bfv[n], acc[m][n]);
    }

#pragma unroll
    for (int m = 0; m < 4; m++)
#pragma unroll
        for (int n = 0; n < 4; n++)
#pragma unroll
            for (int r = 0; r < 4; r++) {
                int row = row0 + wr * 64 + m * 16 + lhi * 4 + r;
                int col = col0 + wc * 64 + n * 16 + llo;
                float v = acc[m][n][r];
                if (OBF) ((short*)C)[(size_t)row * N + col] = f2bf(v);
                else     ((float*)C)[(size_t)row * N + col] = v;
            }
}

// ---------- kernel 3: RoPE + RMSNorm, vectorized bf16x8, q & k in one launch ----------
// blockIdx.y: 0 -> Q (scale QSCALE), 1 -> K (scale 1.0).
// 8 threads per 64-d row; each thread handles 8 consecutive d.
__global__ __launch_bounds__(256) void rope2(
    const short* __restrict__ Qb, const short* __restrict__ Kb,
    const float* __restrict__ cosT, const float* __restrict__ sinT,
    short* __restrict__ qnb, short* __restrict__ knb)
{
    int z = blockIdx.y;
    const short* src = z ? Kb : Qb;
    short* dst = z ? knb : qnb;
    float osc = z ? 1.0f : QSCALE;

    int rowg = blockIdx.x * 32 + (threadIdx.x >> 3);   // t*16 + h
    int t = rowg >> 4, h = rowg & 15;
    int j = threadIdx.x & 7;

    bf16x8 v8 = *(const bf16x8*)&src[(size_t)t * C_DIM + h * HEAD_DIM + j * 8];
    float f[8], o[8];
#pragma unroll
    for (int i = 0; i < 8; i++) f[i] = bf2f(v8[i]);
#pragma unroll
    for (int i = 0; i < 8; i++) o[i] = __shfl_xor(f[i], 4);

    const float* cp = &cosT[t * 32 + (j & 3) * 8];
    const float* sp = &sinT[t * 32 + (j & 3) * 8];
    float4 c0 = *(const float4*)&cp[0], c1 = *(const float4*)&cp[4];
    float4 s0 = *(const float4*)&sp[0], s1 = *(const float4*)&sp[4];
    float cc[8] = {c0.x, c0.y, c0.z, c0.w, c1.x, c1.y, c1.z, c1.w};
    float ss[8] = {s0.x, s0.y, s0.z, s0.w, s1.x, s1.y, s1.z, s1.w};

    float r[8];
    if (j < 4) {
#pragma unroll
        for (int i = 0; i < 8; i++) r[i] = f[i] * cc[i] + o[i] * ss[i];
    } else {
#pragma unroll
        for (int i = 0; i < 8; i++) r[i] = f[i] * cc[i] - o[i] * ss[i];
    }

    float sq = 0.f;
#pragma unroll
    for (int i = 0; i < 8; i++) sq += r[i] * r[i];
#pragma unroll
    for (int off = 1; off <= 4; off <<= 1) sq += __shfl_xor(sq, off);
    float inv = rsqrtf(sq * (1.0f / 64.0f) + 1e-6f) * osc;

    bf16x8 out;
#pragma unroll
    for (int i = 0; i < 8; i++) out[i] = f2bf(r[i] * inv);
    *(bf16x8*)&dst[((size_t)h * T_SEQ + t) * HEAD_DIM + j * 8] = out;
}

// ---------- kernel 4: V transpose [T][C] -> [H][D][T] bf16, scaled ----------
__global__ __launch_bounds__(256) void vtrans(
    const short* __restrict__ Vb, short* __restrict__ vt)
{
    __shared__ short sT[64 * 65];
    int h = blockIdx.y, tb = blockIdx.x;
    int tid = threadIdx.x;
    const float inv64 = 1.0f / (64.0f + 1e-6f);
#pragma unroll
    for (int i = 0; i < 16; i++) {
        int linear = i * 256 + tid;
        int r = linear >> 6, c = linear & 63;
        float v = bf2f(Vb[(size_t)(tb * 64 + r) * C_DIM + h * HEAD_DIM + c]) * inv64;
        sT[c * 65 + r] = f2bf(v);
    }
    __syncthreads();
#pragma unroll
    for (int i = 0; i < 16; i++) {
        int linear = i * 256 + tid;
        int dd = linear >> 6, tt = linear & 63;
        vt[((size_t)(h * HEAD_DIM + dd)) * T_SEQ + tb * 64 + tt] = sT[dd * 65 + tt];
    }
}

// ---------- kernel 5: attention, 4-wave blocks, LDS-staged K/V pipeline ----------
// qn: [H][T][D] pre-scaled -log2e/8; kn: [H][T][D]; vt: [H][D][T] pre-scaled.
// Grid 1024 = 16 heads x 64 q-tiles(64 rows). Block: 4 waves = 2 q-bands(32)
// x 2 kv-teams(32 of each 64-kv step). 4 blocks/CU; per-CU t-quadruple
// {63-k, k, 47-k, 16+k} sums constant for balance. K[64][64]+V[64][64] LDS
// dbuf (32KB) staged via source-swizzled global_load_lds; counted vmcnt(4)
// keeps next stage in flight. P path in registers (cvt_pk + permlane32_swap).

#define STAGE6(s_, bf_) do {                                                     \
    int kb_ = (s_) * 64;                                                         \
    int r_  = lane >> 3;                                                         \
    int ss_ = (lane & 7) ^ r_;                                                   \
    __builtin_amdgcn_global_load_lds(                                            \
        GAS(Kh + (size_t)(kb_ + wv * 16 + r_) * HEAD_DIM + ss_ * 8),             \
        LAS(Smem + (bf_) * 8192 + (wv * 16) * 128), 16, 0, 0);                   \
    __builtin_amdgcn_global_load_lds(                                            \
        GAS(Kh + (size_t)(kb_ + wv * 16 + 8 + r_) * HEAD_DIM + ss_ * 8),         \
        LAS(Smem + (bf_) * 8192 + (wv * 16 + 8) * 128), 16, 0, 0);               \
    __builtin_amdgcn_global_load_lds(                                            \
        GAS(Vh + (size_t)(wv * 16 + r_) * T_SEQ + kb_ + ss_ * 8),                \
        LAS(Smem + 16384 + (bf_) * 8192 + (wv * 16) * 128), 16, 0, 0);           \
    __builtin_amdgcn_global_load_lds(                                            \
        GAS(Vh + (size_t)(wv * 16 + 8 + r_) * T_SEQ + kb_ + ss_ * 8),            \
        LAS(Smem + 16384 + (bf_) * 8192 + (wv * 16 + 8) * 128), 16, 0, 0);       \
} while (0)

__global__ __launch_bounds__(256, 4) void attn6(
    const short* __restrict__ qn, const short* __restrict__ kn,
    const short* __restrict__ vt, short* __restrict__ yb)
{
    __shared__ alignas(16) char Smem[32768];   // K dbuf 16K | V dbuf 16K; Yred overlay

    int id = blockIdx.x;
    int h  = id & 15;
    int g  = id >> 4;                                // 0..63
    int t  = (g < 16) ? (63 - g) : (g < 32) ? (g - 16)
           : (g < 48) ? (79 - g) : (g - 32);         // per-CU quadruple sums const
    int ns = t + 1;                                  // 64-kv steps

    int tid = threadIdx.x, wv = tid >> 6, lane = tid & 63;
    int lo = lane & 31, hi = lane >> 5;
    int band = wv & 1, tm = wv >> 1;

    const short* Qh = qn + (size_t)h * T_SEQ * HEAD_DIM;
    const short* Kh = kn + (size_t)h * T_SEQ * HEAD_DIM;
    const short* Vh = vt + (size_t)h * HEAD_DIM * T_SEQ;

    int q0 = t * 64;
    int qrow  = q0 + band * 32 + lo;
    int qmaxw = q0 + band * 32 + 31;

    const short* Qr = &Qh[(size_t)qrow * HEAD_DIM + hi * 8];
    bf16x8 qf0 = *(const bf16x8*)&Qr[0];
    bf16x8 qf1 = *(const bf16x8*)&Qr[16];
    bf16x8 qf2 = *(const bf16x8*)&Qr[32];
    bf16x8 qf3 = *(const bf16x8*)&Qr[48];

    f32x16 zed;
#pragma unroll
    for (int r = 0; r < 16; r++) zed[r] = 0.f;

    f32x16 yac0, yac1;
#pragma unroll
    for (int r = 0; r < 16; r++) { yac0[r] = 0.f; yac1[r] = 0.f; }

    // loop-invariant LDS byte offsets (swizzled reads)
    unsigned sw   = (unsigned)((lo & 7) << 4);
    unsigned krow = (unsigned)((tm * 32 + lo) * 128);
    unsigned ko0 = krow + ((0u * 32 + hi * 16) ^ sw);
    unsigned ko1 = krow + ((1u * 32 + hi * 16) ^ sw);
    unsigned ko2 = krow + ((2u * 32 + hi * 16) ^ sw);
    unsigned ko3 = krow + ((3u * 32 + hi * 16) ^ sw);
    unsigned vrow0 = (unsigned)(lo * 128)        + 16384u;
    unsigned vrow1 = (unsigned)((32 + lo) * 128) + 16384u;
    unsigned vo00 = vrow0 + (((unsigned)(tm * 64 + 0 * 32 + hi * 16)) ^ sw);
    unsigned vo01 = vrow0 + (((unsigned)(tm * 64 + 1 * 32 + hi * 16)) ^ sw);
    unsigned vo10 = vrow1 + (((unsigned)(tm * 64 + 0 * 32 + hi * 16)) ^ sw);
    unsigned vo11 = vrow1 + (((unsigned)(tm * 64 + 1 * 32 + hi * 16)) ^ sw);

    STAGE6(0, 0);
    int buf = 0;
    for (int s = 0; s < ns; s++) {
        if (s + 1 < ns) {
            STAGE6(s + 1, buf ^ 1);
            asm volatile("s_waitcnt vmcnt(4)" ::: "memory");
        } else {
            asm volatile("s_waitcnt vmcnt(0)" ::: "memory");
        }
        __builtin_amdgcn_s_barrier();

        int kb0 = s * 64 + tm * 32;
        if (kb0 <= qmaxw) {
            const char* B_ = Smem + (buf << 13);
            bf16x8 kf0 = *(const bf16x8*)(B_ + ko0);
            bf16x8 kf1 = *(const bf16x8*)(B_ + ko1);
            bf16x8 kf2 = *(const bf16x8*)(B_ + ko2);
            bf16x8 kf3 = *(const bf16x8*)(B_ + ko3);
            bf16x8 vf00 = *(const bf16x8*)(B_ + vo00);
            bf16x8 vf01 = *(const bf16x8*)(B_ + vo01);
            bf16x8 vf10 = *(const bf16x8*)(B_ + vo10);
            bf16x8 vf11 = *(const bf16x8*)(B_ + vo11);

            f32x16 sv;
            __builtin_amdgcn_s_setprio(1);
            sv = mfma32(kf0, qf0, zed);
            sv = mfma32(kf1, qf1, sv);
            sv = mfma32(kf2, qf2, sv);
            sv = mfma32(kf3, qf3, sv);
            __builtin_amdgcn_s_setprio(0);

            if (kb0 + 31 > q0 + band * 32) {         // diagonal chunk: element mask
#pragma unroll
                for (int r = 0; r < 16; r++) {
                    int kvg = kb0 + (r & 3) + 8 * (r >> 2) + 4 * hi;
                    float pv = __builtin_amdgcn_rcpf(1.f + exp2_hw(sv[r]));
                    sv[r] = (kvg <= qrow) ? pv : 0.f;
                }
            } else {
#pragma unroll
                for (int r = 0; r < 16; r++)
                    sv[r] = __builtin_amdgcn_rcpf(1.f + exp2_hw(sv[r]));
            }

#pragma unroll
            for (int k2 = 0; k2 < 2; k2++) {
                unsigned wA = cvt_pk_bf16(sv[8 * k2 + 0], sv[8 * k2 + 1]);
                unsigned wC = cvt_pk_bf16(sv[8 * k2 + 2], sv[8 * k2 + 3]);
                unsigned wB = cvt_pk_bf16(sv[8 * k2 + 4], sv[8 * k2 + 5]);
                unsigned wD = cvt_pk_bf16(sv[8 * k2 + 6], sv[8 * k2 + 7]);
                plane_swap(wA, wB);
                plane_swap(wC, wD);
                union { unsigned u[4]; bf16x8 v; } pw;
                pw.u[0] = wA; pw.u[1] = wC; pw.u[2] = wB; pw.u[3] = wD;
                __builtin_amdgcn_s_setprio(1);
                yac0 = mfma32(pw.v, k2 ? vf01 : vf00, yac0);
                yac1 = mfma32(pw.v, k2 ? vf11 : vf10, yac1);
                __builtin_amdgcn_s_setprio(0);
            }
        }
        asm volatile("" ::: "memory");
        __builtin_amdgcn_s_barrier();
        buf ^= 1;
    }

    // ---- cross-team reduce (kv halves) + store ----
    __syncthreads();
    float* Yred = (float*)Smem;                      // [2 band][32 q][64 d] overlay
    if (tm == 1) {
#pragma unroll
        for (int d = 0; d < 2; d++)
#pragma unroll
            for (int r = 0; r < 16; r++) {
                int crow = (r & 3) + 8 * (r >> 2) + 4 * hi;
                Yred[(band * 32 + crow) * 64 + d * 32 + lo] = d ? yac1[r] : yac0[r];
            }
    }
    __syncthreads();
    if (tm == 0) {
#pragma unroll
        for (int d = 0; d < 2; d++)
#pragma unroll
            for (int r = 0; r < 16; r++) {
                int crow = (r & 3) + 8 * (r >> 2) + 4 * hi;
                float v = (d ? yac1[r] : yac0[r]) + Yred[(band * 32 + crow) * 64 + d * 32 + lo];
                yb[(size_t)(q0 + band * 32 + crow) * C_DIM + h * HEAD_DIM + d * 32 + lo] = f2bf(v);
            }
    }
}

// ---------- launch ----------
extern "C" void kernel_launch(void* const* d_in, const int* in_sizes, int n_in,
                              void* d_out, int out_size, void* d_ws, size_t ws_size,
                              hipStream_t stream)
{
    const float* x    = (const float*)d_in[0];
    const float* cosT = (const float*)d_in[1];
    const float* sinT = (const float*)d_in[2];
    const float* wq   = (const float*)d_in[3];
    const float* wk   = (const float*)d_in[4];
    const float* wv   = (const float*)d_in[5];
    const float* wp   = (const float*)d_in[6];

    char* ws = (char*)d_ws;
    const size_t MB = 1024 * 1024;
    short* xb  = (short*)(ws + 0);
    short* wqb = (short*)(ws + 8  * MB);
    short* wkb = (short*)(ws + 10 * MB);
    short* wvb = (short*)(ws + 12 * MB);
    short* wpb = (short*)(ws + 14 * MB);
    short* Qb  = (short*)(ws + 16 * MB);
    short* Kb  = (short*)(ws + 24 * MB);
    short* Vb  = (short*)(ws + 32 * MB);
    short* qnb = (short*)(ws + 40 * MB);
    short* knb = (short*)(ws + 48 * MB);
    short* vtb = (short*)(ws + 56 * MB);
    short* yb  = (short*)(ws + 64 * MB);

    cast5<<<dim3(4096, 5, 1), 256, 0, stream>>>(
        x, wq, wk, wv, wp, xb, wqb, wkb, wvb, wpb,
        T_SEQ * C_DIM, C_DIM * C_DIM, C_DIM * C_DIM, C_DIM * C_DIM, C_DIM * C_DIM);

    gemm3<1><<<dim3(32, 8, 3), 256, 0, stream>>>(
        xb, wqb, wkb, wvb, (void*)Qb, (void*)Kb, (void*)Vb, T_SEQ, C_DIM, C_DIM);

    rope2<<<dim3(2048, 2, 1), 256, 0, stream>>>(Qb, Kb, cosT, sinT, qnb, knb);

    vtrans<<<dim3(64, 16, 1), 256, 0, stream>>>(Vb, vtb);

    attn6<<<1024, 256, 0, stream>>>(qnb, knb, vtb, yb);

    gemm3<0><<<dim3(32, 8, 1), 256, 0, stream>>>(
        yb, wpb, wpb, wpb, d_out, d_out, d_out, T_SEQ, C_DIM, C_DIM);
}